// Round 2
// baseline (372.092 us; speedup 1.0000x reference)
//
#include <hip/hip_runtime.h>

// LongformerAttention on MI355X (gfx950), fp16 MFMA pipeline, round 2.
// R2 changes: (1) attention computes S^T = K*Q^T so the P fragment feeds PV's
// 16x16x16 mfma B-operand straight from registers (no P LDS round-trip,
// LDS 67.6->32 KB => 4 blocks/CU); (2) RoPE fused into gemm_qkv epilogue via
// __shfl_xor(val,1) pair rotation (rope kernel deleted).

typedef _Float16 half8 __attribute__((ext_vector_type(8)));
typedef _Float16 half4v __attribute__((ext_vector_type(4)));
typedef float floatx4 __attribute__((ext_vector_type(4)));

typedef __attribute__((address_space(3))) unsigned int lds_u32;
typedef const __attribute__((address_space(1))) unsigned int glb_u32;

__device__ __forceinline__ void async_copy16(const void* g, void* l) {
  // global -> LDS direct, 16 B/lane. LDS dest = wave-uniform base + lane*16.
  __builtin_amdgcn_global_load_lds((glb_u32*)g, (lds_u32*)l, 16, 0, 0);
}

// ---------------------------------------------------------------- convert
__global__ __launch_bounds__(256) void convert_kernel(
    const float* __restrict__ x, const float* __restrict__ wq,
    const float* __restrict__ wk, const float* __restrict__ wv,
    const float* __restrict__ wo, _Float16* __restrict__ dst) {
  const int e0 = (blockIdx.x * 256 + threadIdx.x) * 4;
  const float* src; int off;
  if      (e0 <  8388608) { src = x;  off = e0; }
  else if (e0 <  9437184) { src = wq; off = e0 -  8388608; }
  else if (e0 < 10485760) { src = wk; off = e0 -  9437184; }
  else if (e0 < 11534336) { src = wv; off = e0 - 10485760; }
  else                    { src = wo; off = e0 - 11534336; }
  const float4 f = *(const float4*)(src + off);
  half4v h;
  h[0] = (_Float16)f.x; h[1] = (_Float16)f.y;
  h[2] = (_Float16)f.z; h[3] = (_Float16)f.w;
  *(half4v*)(dst + e0) = h;
}

// ---------------------------------------------------------------- QKV GEMM
// out[m,n] = sum_k A[m,k]*W[n,k] + bias[n], then (for q,k) RoPE fused in the
// epilogue: pair (n, n^1) lives in adjacent l4 lanes -> __shfl_xor(val, 1).
// q additionally scaled by log2(e)/8 (softmax runs in exp2 domain).
__global__ __launch_bounds__(256, 2) void gemm_qkv_kernel(
    const _Float16* __restrict__ A, const _Float16* __restrict__ w0,
    const _Float16* __restrict__ w1, const _Float16* __restrict__ w2,
    const float* __restrict__ b0, const float* __restrict__ b1,
    const float* __restrict__ b2, _Float16* __restrict__ o0,
    _Float16* __restrict__ o1, _Float16* __restrict__ o2) {
  __shared__ _Float16 As[128 * 32];
  __shared__ _Float16 Bs[128 * 32];
  const int tid = threadIdx.x;
  const int w = tid >> 6, lane = tid & 63;
  const int l4 = lane & 15, quad = lane >> 4;
  const int wm = w & 1, wn = w >> 1;
  const int m0 = blockIdx.x * 128, n0 = blockIdx.y * 128;

  const _Float16* B; const float* bias; _Float16* out;
  if (blockIdx.z == 0)      { B = w0; bias = b0; out = o0; }
  else if (blockIdx.z == 1) { B = w1; bias = b1; out = o1; }
  else                      { B = w2; bias = b2; out = o2; }
  const bool dorope = blockIdx.z < 2;
  const float scl = (blockIdx.z == 0) ? 0.18033688f : 1.0f;  // log2e/8

  const floatx4 zero = {0.f, 0.f, 0.f, 0.f};
  floatx4 acc[4][4];
#pragma unroll
  for (int i = 0; i < 4; ++i)
#pragma unroll
    for (int j = 0; j < 4; ++j) acc[i][j] = zero;

  const int fcb = (quad ^ ((l4 >> 2) & 3)) * 8;  // swizzled frag colblock

  for (int kt = 0; kt < 32; ++kt) {
    const int k0 = kt * 32;
#pragma unroll
    for (int i = 0; i < 2; ++i) {
      const int p = i * 256 + tid;
      const int r = p >> 2;
      const int cb = (p & 3) ^ ((r >> 2) & 3);
      async_copy16(A + (m0 + r) * 1024 + k0 + cb * 8, As + (i * 256 + w * 64) * 8);
      async_copy16(B + (n0 + r) * 1024 + k0 + cb * 8, Bs + (i * 256 + w * 64) * 8);
    }
    __syncthreads();
    half8 af[4], bf[4];
#pragma unroll
    for (int mt = 0; mt < 4; ++mt)
      af[mt] = *(const half8*)(As + (wm * 64 + mt * 16 + l4) * 32 + fcb);
#pragma unroll
    for (int nt = 0; nt < 4; ++nt)
      bf[nt] = *(const half8*)(Bs + (wn * 64 + nt * 16 + l4) * 32 + fcb);
#pragma unroll
    for (int mt = 0; mt < 4; ++mt)
#pragma unroll
      for (int nt = 0; nt < 4; ++nt)
        acc[mt][nt] = __builtin_amdgcn_mfma_f32_16x16x32_f16(af[mt], bf[nt], acc[mt][nt], 0, 0, 0);
    __syncthreads();
  }

#pragma unroll
  for (int nt = 0; nt < 4; ++nt) {
    const int n = n0 + wn * 64 + nt * 16 + l4;
    const float bval = bias[n];
    const int hh = n >> 6, dd = n & 63;
    // RoPE angle: theta = h * 10000^(-((n&63) mod 32)/32); per-nt constant per lane
    float c_ = 1.f, ss = 0.f;
    if (dorope) {
      const float freq = __expf((float)(n & 31) * -0.28782314f);  // ln(1e4)/32
      float s_;
      __sincosf((float)hh * freq, &s_, &c_);
      ss = (n & 1) ? s_ : -s_;  // even j: -x[j+1]*sin; odd j: +x[j-1]*sin
    }
#pragma unroll
    for (int mt = 0; mt < 4; ++mt)
#pragma unroll
      for (int r = 0; r < 4; ++r) {
        const int m = m0 + wm * 64 + mt * 16 + quad * 4 + r;  // C row = quad*4+reg
        const int bb = m >> 12, s = m & 4095;
        float val = acc[mt][nt][r] + bval;
        const float prt = __shfl_xor(val, 1);
        if (dorope) val = (val * c_ + prt * ss) * scl;
        out[((bb * 16 + hh) * 4096 + s) * 64 + dd] = (_Float16)val;
      }
  }
}

// ---------------------------------------------------------------- out GEMM
__global__ __launch_bounds__(256, 2) void gemm_out_kernel(
    const _Float16* __restrict__ A, const _Float16* __restrict__ B,
    const float* __restrict__ bias, float* __restrict__ out) {
  __shared__ _Float16 As[128 * 32];
  __shared__ _Float16 Bs[128 * 32];
  const int tid = threadIdx.x;
  const int w = tid >> 6, lane = tid & 63;
  const int l4 = lane & 15, quad = lane >> 4;
  const int wm = w & 1, wn = w >> 1;
  const int m0 = blockIdx.x * 128, n0 = blockIdx.y * 128;

  const floatx4 zero = {0.f, 0.f, 0.f, 0.f};
  floatx4 acc[4][4];
#pragma unroll
  for (int i = 0; i < 4; ++i)
#pragma unroll
    for (int j = 0; j < 4; ++j) acc[i][j] = zero;

  const int fcb = (quad ^ ((l4 >> 2) & 3)) * 8;

  for (int kt = 0; kt < 32; ++kt) {
    const int k0 = kt * 32;
#pragma unroll
    for (int i = 0; i < 2; ++i) {
      const int p = i * 256 + tid;
      const int r = p >> 2;
      const int cb = (p & 3) ^ ((r >> 2) & 3);
      async_copy16(A + (m0 + r) * 1024 + k0 + cb * 8, As + (i * 256 + w * 64) * 8);
      async_copy16(B + (n0 + r) * 1024 + k0 + cb * 8, Bs + (i * 256 + w * 64) * 8);
    }
    __syncthreads();
    half8 af[4], bf[4];
#pragma unroll
    for (int mt = 0; mt < 4; ++mt)
      af[mt] = *(const half8*)(As + (wm * 64 + mt * 16 + l4) * 32 + fcb);
#pragma unroll
    for (int nt = 0; nt < 4; ++nt)
      bf[nt] = *(const half8*)(Bs + (wn * 64 + nt * 16 + l4) * 32 + fcb);
#pragma unroll
    for (int mt = 0; mt < 4; ++mt)
#pragma unroll
      for (int nt = 0; nt < 4; ++nt)
        acc[mt][nt] = __builtin_amdgcn_mfma_f32_16x16x32_f16(af[mt], bf[nt], acc[mt][nt], 0, 0, 0);
    __syncthreads();
  }

#pragma unroll
  for (int nt = 0; nt < 4; ++nt) {
    const int n = n0 + wn * 64 + nt * 16 + l4;
    const float bval = bias[n];
#pragma unroll
    for (int mt = 0; mt < 4; ++mt)
#pragma unroll
      for (int r = 0; r < 4; ++r) {
        const int m = m0 + wm * 64 + mt * 16 + quad * 4 + r;
        out[m * 1024 + n] = acc[mt][nt][r] + bval;
      }
  }
}

// ---------------------------------------------------------------- V transpose
__global__ __launch_bounds__(256) void transpose_v(const _Float16* __restrict__ v,
                                                   _Float16* __restrict__ vt) {
  __shared__ _Float16 tile[64 * 70];
  const int t = threadIdx.x;
  const int bh = blockIdx.y, s0 = blockIdx.x * 64;
  const _Float16* src = v + (bh * 4096 + s0) * 64;
#pragma unroll
  for (int i = 0; i < 2; ++i) {
    const int c = i * 256 + t;
    const int row = c >> 3, cb = c & 7;
    const half8 d = *(const half8*)(src + row * 64 + cb * 8);
#pragma unroll
    for (int u = 0; u < 8; ++u) tile[(cb * 8 + u) * 70 + row] = d[u];
  }
  __syncthreads();
  _Float16* dst = vt + bh * 262144 + s0;
#pragma unroll
  for (int i = 0; i < 2; ++i) {
    const int c = i * 256 + t;
    const int dd = c >> 3, scb = c & 7;
    half8 d;
#pragma unroll
    for (int u = 0; u < 8; ++u) d[u] = tile[dd * 70 + scb * 8 + u];
    *(half8*)(dst + dd * 4096 + scb * 8) = d;
  }
}

// ---------------------------------------------------------------- attention
// S^T formulation: per tile compute ST = K*Q^T (A=K-frags rows=keys, B=Q-frags
// cols=queries). ST's C-layout (row=quad*4+r=key, col=l4=query) IS the
// B-operand layout of mfma_f32_16x16x16_f16 (k=quad*4+j, n=l4), so P feeds
// PV directly from registers after fp32->fp16 convert. O comes out transposed
// (rows=d, cols=query). Softmax rows are queries = lane-local + 2 shuffles.
__global__ __launch_bounds__(256, 4) void attn_kernel(
    const _Float16* __restrict__ qg, const _Float16* __restrict__ kg,
    const _Float16* __restrict__ vtg, _Float16* __restrict__ ctx) {
  __shared__ _Float16 Ks[128 * 64];   // [key][d]
  __shared__ _Float16 Vs[64 * 128];   // [d][key] (from vt)

  const int tid = threadIdx.x;
  const int w = tid >> 6, lane = tid & 63;
  const int l4 = lane & 15, quad = lane >> 4;
  const int q0 = blockIdx.x * 128;
  const int bh = blockIdx.y;
  const _Float16* qbh = qg + bh * 262144;
  const _Float16* kbh = kg + bh * 262144;
  const _Float16* vbh = vtg + bh * 262144;

  // Q as B-operand frags: query = w*32 + nt*16 + l4, d = ks*32 + quad*8..+7
  half8 qf[2][2];
#pragma unroll
  for (int nt = 0; nt < 2; ++nt)
#pragma unroll
    for (int ks = 0; ks < 2; ++ks)
      qf[nt][ks] = *(const half8*)(qbh + (q0 + w * 32 + nt * 16 + l4) * 64 + ks * 32 + quad * 8);

  const floatx4 zero = {0.f, 0.f, 0.f, 0.f};
  floatx4 OT[4][2];                  // [d-tile][q-tile], row=quad*4+r=d, col=l4=query
  float m_st[2], l_st[2];
#pragma unroll
  for (int md = 0; md < 4; ++md)
#pragma unroll
    for (int nt = 0; nt < 2; ++nt) OT[md][nt] = zero;
#pragma unroll
  for (int nt = 0; nt < 2; ++nt) { m_st[nt] = -1e30f; l_st[nt] = 0.f; }

  for (int t = 0; t < 5; ++t) {
    const int kv0 = q0 + (t - 2) * 128;
    if (kv0 < 0 || kv0 >= 4096) continue;  // block-uniform

    // stage K [128][64] and Vt [64][128], 3-bit XOR chunk swizzle
#pragma unroll
    for (int i = 0; i < 4; ++i) {
      const int p = i * 256 + tid;
      const int rk = p >> 3, ck = (p & 7) ^ (rk & 7);
      async_copy16(kbh + (kv0 + rk) * 64 + ck * 8, Ks + (i * 256 + w * 64) * 8);
      const int rv = p >> 4, cv = (p & 15) ^ (rv & 7);
      async_copy16(vbh + rv * 4096 + kv0 + cv * 8, Vs + (i * 256 + w * 64) * 8);
    }
    __syncthreads();

    // ST = K Q^T : 128 keys (8 mtiles) x 32 queries (2 ntiles)
    floatx4 ST[8][2];
#pragma unroll
    for (int m = 0; m < 8; ++m)
#pragma unroll
      for (int nt = 0; nt < 2; ++nt) ST[m][nt] = zero;
#pragma unroll
    for (int ks = 0; ks < 2; ++ks)
#pragma unroll
      for (int m = 0; m < 8; ++m) {
        const half8 kf = *(const half8*)(Ks + (m * 16 + l4) * 64 + ((ks * 4 + quad) ^ (l4 & 7)) * 8);
#pragma unroll
        for (int nt = 0; nt < 2; ++nt)
          ST[m][nt] = __builtin_amdgcn_mfma_f32_16x16x32_f16(kf, qf[nt][ks], ST[m][nt], 0, 0, 0);
      }

    if (t == 0 || t == 4) {  // only edge tiles are banded
#pragma unroll
      for (int m = 0; m < 8; ++m)
#pragma unroll
        for (int r = 0; r < 4; ++r) {
          const int key = kv0 + m * 16 + quad * 4 + r;
#pragma unroll
          for (int nt = 0; nt < 2; ++nt) {
            const int d = key - (q0 + w * 32 + nt * 16 + l4);
            if (d < -256 || d > 256) ST[m][nt][r] = -1e30f;
          }
        }
    }

    // online softmax per query column (lane-local over 32 keys + 2 shuffles)
    float alpha[2];
#pragma unroll
    for (int nt = 0; nt < 2; ++nt) {
      float mx = -1e30f;
#pragma unroll
      for (int m = 0; m < 8; ++m)
#pragma unroll
        for (int r = 0; r < 4; ++r) mx = fmaxf(mx, ST[m][nt][r]);
      mx = fmaxf(mx, __shfl_xor(mx, 16));
      mx = fmaxf(mx, __shfl_xor(mx, 32));
      const float mnew = fmaxf(m_st[nt], mx);
      alpha[nt] = exp2f(m_st[nt] - mnew);
      m_st[nt] = mnew;
      float rs = 0.f;
#pragma unroll
      for (int m = 0; m < 8; ++m)
#pragma unroll
        for (int r = 0; r < 4; ++r) {
          const float pv = exp2f(ST[m][nt][r] - mnew);
          ST[m][nt][r] = pv;
          rs += pv;
        }
      rs += __shfl_xor(rs, 16);
      rs += __shfl_xor(rs, 32);
      l_st[nt] = l_st[nt] * alpha[nt] + rs;
#pragma unroll
      for (int md = 0; md < 4; ++md)
#pragma unroll
        for (int r = 0; r < 4; ++r) OT[md][nt][r] *= alpha[nt];
    }

    // O^T += V^T P^T via 16x16x16 mfma; P B-frag = packed ST C-frag (k=quad*4+j)
#pragma unroll
    for (int m = 0; m < 8; ++m) {
      half4v pb[2];
#pragma unroll
      for (int nt = 0; nt < 2; ++nt) {
        const auto lo = __builtin_amdgcn_cvt_pkrtz(ST[m][nt][0], ST[m][nt][1]);
        const auto hi = __builtin_amdgcn_cvt_pkrtz(ST[m][nt][2], ST[m][nt][3]);
        pb[nt][0] = (_Float16)lo[0]; pb[nt][1] = (_Float16)lo[1];
        pb[nt][2] = (_Float16)hi[0]; pb[nt][3] = (_Float16)hi[1];
      }
#pragma unroll
      for (int md = 0; md < 4; ++md) {
        // V^T A-frag: m-dim = d = md*16+l4, k = keys m*16 + quad*4..+3 (b64 read)
        const half4v vf = *(const half4v*)(Vs + (md * 16 + l4) * 128 +
                                           ((m * 2 + (quad >> 1)) ^ (l4 & 7)) * 8 + (quad & 1) * 4);
#pragma unroll
        for (int nt = 0; nt < 2; ++nt)
          OT[md][nt] = __builtin_amdgcn_mfma_f32_16x16x16f16(vf, pb[nt], OT[md][nt], 0, 0, 0);
      }
    }
    __syncthreads();  // protect Ks/Vs before next tile's staging
  }

  // epilogue: O^T lane holds (d = md*16+quad*4+r, query = nt*16+l4); r is
  // contiguous in d -> packed half4 (8 B) stores.
  const int b = bh >> 4, hh = bh & 15;
#pragma unroll
  for (int nt = 0; nt < 2; ++nt) {
    const float inv_l = 1.f / l_st[nt];
    const int s = q0 + w * 32 + nt * 16 + l4;
#pragma unroll
    for (int md = 0; md < 4; ++md) {
      half4v o;
#pragma unroll
      for (int r = 0; r < 4; ++r) o[r] = (_Float16)(OT[md][nt][r] * inv_l);
      *(half4v*)(ctx + (b * 4096 + s) * 1024 + hh * 64 + md * 16 + quad * 4) = o;
    }
  }
}

// ---------------------------------------------------------------- launch
extern "C" void kernel_launch(void* const* d_in, const int* in_sizes, int n_in,
                              void* d_out, int out_size, void* d_ws, size_t ws_size,
                              hipStream_t stream) {
  const float* x  = (const float*)d_in[0];
  const float* Wq = (const float*)d_in[1];
  const float* bq = (const float*)d_in[2];
  const float* Wk = (const float*)d_in[3];
  const float* bk = (const float*)d_in[4];
  const float* Wv = (const float*)d_in[5];
  const float* bv = (const float*)d_in[6];
  const float* Wo = (const float*)d_in[7];
  const float* bo = (const float*)d_in[8];

  _Float16* ws   = (_Float16*)d_ws;       // all offsets in halfs
  _Float16* xh   = ws;                    // 8388608
  _Float16* wqh  = ws + 8388608;          // 1048576 each
  _Float16* wkh  = ws + 9437184;
  _Float16* wvh  = ws + 10485760;
  _Float16* woh  = ws + 11534336;
  _Float16* qh   = ws + 12582912;         // [b,h,s,d] fp16, rope+scale applied
  _Float16* kh   = ws + 20971520;         // [b,h,s,d] fp16, rope applied
  _Float16* vh   = ws + 29360128;         // [b,h,s,d] fp16
  _Float16* vth  = ws + 37748736;         // [b,h,d,s]
  _Float16* ctxh = xh;                    // reuse: x dead after QKV GEMM

  convert_kernel<<<12288, 256, 0, stream>>>(x, Wq, Wk, Wv, Wo, ws);
  gemm_qkv_kernel<<<dim3(64, 8, 3), 256, 0, stream>>>(xh, wqh, wkh, wvh,
                                                      bq, bk, bv, qh, kh, vh);
  transpose_v<<<dim3(64, 32), 256, 0, stream>>>(vh, vth);
  attn_kernel<<<dim3(32, 32), 256, 0, stream>>>(qh, kh, vth, ctxh);
  gemm_out_kernel<<<dim3(64, 8), 256, 0, stream>>>(ctxh, woh, bo, (float*)d_out);
}

// Round 3
// 258.387 us; speedup vs baseline: 1.4401x; 1.4401x over previous
//
#include <hip/hip_runtime.h>

// LongformerAttention on MI355X (gfx950), fp16 MFMA pipeline, round 3.
// R3: attention keeps the S^T = K*Q^T register-resident-P formulation from R2
// but processes each 128-key tile in TWO 64-key halves, halving the score
// tile's live registers (ST [8][2]->[4][2], 64->32 VGPRs). R2's regression was
// scratch spill (VGPR cap 64 under launch_bounds(256,4) -> 650 MB HBM spill
// traffic). Back to launch_bounds(256,2), target ~110 VGPRs spill-free.

typedef _Float16 half8 __attribute__((ext_vector_type(8)));
typedef _Float16 half4v __attribute__((ext_vector_type(4)));
typedef float floatx4 __attribute__((ext_vector_type(4)));

typedef __attribute__((address_space(3))) unsigned int lds_u32;
typedef const __attribute__((address_space(1))) unsigned int glb_u32;

__device__ __forceinline__ void async_copy16(const void* g, void* l) {
  // global -> LDS direct, 16 B/lane. LDS dest = wave-uniform base + lane*16.
  __builtin_amdgcn_global_load_lds((glb_u32*)g, (lds_u32*)l, 16, 0, 0);
}

// ---------------------------------------------------------------- convert
__global__ __launch_bounds__(256) void convert_kernel(
    const float* __restrict__ x, const float* __restrict__ wq,
    const float* __restrict__ wk, const float* __restrict__ wv,
    const float* __restrict__ wo, _Float16* __restrict__ dst) {
  const int e0 = (blockIdx.x * 256 + threadIdx.x) * 4;
  const float* src; int off;
  if      (e0 <  8388608) { src = x;  off = e0; }
  else if (e0 <  9437184) { src = wq; off = e0 -  8388608; }
  else if (e0 < 10485760) { src = wk; off = e0 -  9437184; }
  else if (e0 < 11534336) { src = wv; off = e0 - 10485760; }
  else                    { src = wo; off = e0 - 11534336; }
  const float4 f = *(const float4*)(src + off);
  half4v h;
  h[0] = (_Float16)f.x; h[1] = (_Float16)f.y;
  h[2] = (_Float16)f.z; h[3] = (_Float16)f.w;
  *(half4v*)(dst + e0) = h;
}

// ---------------------------------------------------------------- QKV GEMM
// out[m,n] = sum_k A[m,k]*W[n,k] + bias[n], then (for q,k) RoPE fused in the
// epilogue: pair (n, n^1) lives in adjacent l4 lanes -> __shfl_xor(val, 1).
// q additionally scaled by log2(e)/8 (softmax runs in exp2 domain).
__global__ __launch_bounds__(256, 2) void gemm_qkv_kernel(
    const _Float16* __restrict__ A, const _Float16* __restrict__ w0,
    const _Float16* __restrict__ w1, const _Float16* __restrict__ w2,
    const float* __restrict__ b0, const float* __restrict__ b1,
    const float* __restrict__ b2, _Float16* __restrict__ o0,
    _Float16* __restrict__ o1, _Float16* __restrict__ o2) {
  __shared__ _Float16 As[128 * 32];
  __shared__ _Float16 Bs[128 * 32];
  const int tid = threadIdx.x;
  const int w = tid >> 6, lane = tid & 63;
  const int l4 = lane & 15, quad = lane >> 4;
  const int wm = w & 1, wn = w >> 1;
  const int m0 = blockIdx.x * 128, n0 = blockIdx.y * 128;

  const _Float16* B; const float* bias; _Float16* out;
  if (blockIdx.z == 0)      { B = w0; bias = b0; out = o0; }
  else if (blockIdx.z == 1) { B = w1; bias = b1; out = o1; }
  else                      { B = w2; bias = b2; out = o2; }
  const bool dorope = blockIdx.z < 2;
  const float scl = (blockIdx.z == 0) ? 0.18033688f : 1.0f;  // log2e/8

  const floatx4 zero = {0.f, 0.f, 0.f, 0.f};
  floatx4 acc[4][4];
#pragma unroll
  for (int i = 0; i < 4; ++i)
#pragma unroll
    for (int j = 0; j < 4; ++j) acc[i][j] = zero;

  const int fcb = (quad ^ ((l4 >> 2) & 3)) * 8;  // swizzled frag colblock

  for (int kt = 0; kt < 32; ++kt) {
    const int k0 = kt * 32;
#pragma unroll
    for (int i = 0; i < 2; ++i) {
      const int p = i * 256 + tid;
      const int r = p >> 2;
      const int cb = (p & 3) ^ ((r >> 2) & 3);
      async_copy16(A + (m0 + r) * 1024 + k0 + cb * 8, As + (i * 256 + w * 64) * 8);
      async_copy16(B + (n0 + r) * 1024 + k0 + cb * 8, Bs + (i * 256 + w * 64) * 8);
    }
    __syncthreads();
    half8 af[4], bf[4];
#pragma unroll
    for (int mt = 0; mt < 4; ++mt)
      af[mt] = *(const half8*)(As + (wm * 64 + mt * 16 + l4) * 32 + fcb);
#pragma unroll
    for (int nt = 0; nt < 4; ++nt)
      bf[nt] = *(const half8*)(Bs + (wn * 64 + nt * 16 + l4) * 32 + fcb);
#pragma unroll
    for (int mt = 0; mt < 4; ++mt)
#pragma unroll
      for (int nt = 0; nt < 4; ++nt)
        acc[mt][nt] = __builtin_amdgcn_mfma_f32_16x16x32_f16(af[mt], bf[nt], acc[mt][nt], 0, 0, 0);
    __syncthreads();
  }

#pragma unroll
  for (int nt = 0; nt < 4; ++nt) {
    const int n = n0 + wn * 64 + nt * 16 + l4;
    const float bval = bias[n];
    const int hh = n >> 6, dd = n & 63;
    // RoPE angle: theta = h * 10000^(-((n&63) mod 32)/32); per-nt constant per lane
    float c_ = 1.f, ss = 0.f;
    if (dorope) {
      const float freq = __expf((float)(n & 31) * -0.28782314f);  // ln(1e4)/32
      float s_;
      __sincosf((float)hh * freq, &s_, &c_);
      ss = (n & 1) ? s_ : -s_;  // even j: -x[j+1]*sin; odd j: +x[j-1]*sin
    }
#pragma unroll
    for (int mt = 0; mt < 4; ++mt)
#pragma unroll
      for (int r = 0; r < 4; ++r) {
        const int m = m0 + wm * 64 + mt * 16 + quad * 4 + r;  // C row = quad*4+reg
        const int bb = m >> 12, s = m & 4095;
        float val = acc[mt][nt][r] + bval;
        const float prt = __shfl_xor(val, 1);
        if (dorope) val = (val * c_ + prt * ss) * scl;
        out[((bb * 16 + hh) * 4096 + s) * 64 + dd] = (_Float16)val;
      }
  }
}

// ---------------------------------------------------------------- out GEMM
__global__ __launch_bounds__(256, 2) void gemm_out_kernel(
    const _Float16* __restrict__ A, const _Float16* __restrict__ B,
    const float* __restrict__ bias, float* __restrict__ out) {
  __shared__ _Float16 As[128 * 32];
  __shared__ _Float16 Bs[128 * 32];
  const int tid = threadIdx.x;
  const int w = tid >> 6, lane = tid & 63;
  const int l4 = lane & 15, quad = lane >> 4;
  const int wm = w & 1, wn = w >> 1;
  const int m0 = blockIdx.x * 128, n0 = blockIdx.y * 128;

  const floatx4 zero = {0.f, 0.f, 0.f, 0.f};
  floatx4 acc[4][4];
#pragma unroll
  for (int i = 0; i < 4; ++i)
#pragma unroll
    for (int j = 0; j < 4; ++j) acc[i][j] = zero;

  const int fcb = (quad ^ ((l4 >> 2) & 3)) * 8;

  for (int kt = 0; kt < 32; ++kt) {
    const int k0 = kt * 32;
#pragma unroll
    for (int i = 0; i < 2; ++i) {
      const int p = i * 256 + tid;
      const int r = p >> 2;
      const int cb = (p & 3) ^ ((r >> 2) & 3);
      async_copy16(A + (m0 + r) * 1024 + k0 + cb * 8, As + (i * 256 + w * 64) * 8);
      async_copy16(B + (n0 + r) * 1024 + k0 + cb * 8, Bs + (i * 256 + w * 64) * 8);
    }
    __syncthreads();
    half8 af[4], bf[4];
#pragma unroll
    for (int mt = 0; mt < 4; ++mt)
      af[mt] = *(const half8*)(As + (wm * 64 + mt * 16 + l4) * 32 + fcb);
#pragma unroll
    for (int nt = 0; nt < 4; ++nt)
      bf[nt] = *(const half8*)(Bs + (wn * 64 + nt * 16 + l4) * 32 + fcb);
#pragma unroll
    for (int mt = 0; mt < 4; ++mt)
#pragma unroll
      for (int nt = 0; nt < 4; ++nt)
        acc[mt][nt] = __builtin_amdgcn_mfma_f32_16x16x32_f16(af[mt], bf[nt], acc[mt][nt], 0, 0, 0);
    __syncthreads();
  }

#pragma unroll
  for (int nt = 0; nt < 4; ++nt) {
    const int n = n0 + wn * 64 + nt * 16 + l4;
    const float bval = bias[n];
#pragma unroll
    for (int mt = 0; mt < 4; ++mt)
#pragma unroll
      for (int r = 0; r < 4; ++r) {
        const int m = m0 + wm * 64 + mt * 16 + quad * 4 + r;
        out[m * 1024 + n] = acc[mt][nt][r] + bval;
      }
  }
}

// ---------------------------------------------------------------- V transpose
__global__ __launch_bounds__(256) void transpose_v(const _Float16* __restrict__ v,
                                                   _Float16* __restrict__ vt) {
  __shared__ _Float16 tile[64 * 70];
  const int t = threadIdx.x;
  const int bh = blockIdx.y, s0 = blockIdx.x * 64;
  const _Float16* src = v + (bh * 4096 + s0) * 64;
#pragma unroll
  for (int i = 0; i < 2; ++i) {
    const int c = i * 256 + t;
    const int row = c >> 3, cb = c & 7;
    const half8 d = *(const half8*)(src + row * 64 + cb * 8);
#pragma unroll
    for (int u = 0; u < 8; ++u) tile[(cb * 8 + u) * 70 + row] = d[u];
  }
  __syncthreads();
  _Float16* dst = vt + bh * 262144 + s0;
#pragma unroll
  for (int i = 0; i < 2; ++i) {
    const int c = i * 256 + t;
    const int dd = c >> 3, scb = c & 7;
    half8 d;
#pragma unroll
    for (int u = 0; u < 8; ++u) d[u] = tile[dd * 70 + scb * 8 + u];
    *(half8*)(dst + dd * 4096 + scb * 8) = d;
  }
}

// ---------------------------------------------------------------- attention
// S^T formulation: ST = K*Q^T per 64-key half-tile (A=K-frags rows=keys,
// B=Q-frags cols=queries). ST's C-layout (row=quad*4+r=key, col=l4=query) IS
// the B-operand layout of mfma_f32_16x16x16f16 (k=quad*4+j, n=l4): P feeds PV
// directly from registers. Two 64-key halves per staged 128-key tile keep ST
// at [4][2]=32 VGPRs (R2's [8][2]=64 spilled at the 64-VGPR cap).
__global__ __launch_bounds__(256, 2) void attn_kernel(
    const _Float16* __restrict__ qg, const _Float16* __restrict__ kg,
    const _Float16* __restrict__ vtg, _Float16* __restrict__ ctx) {
  __shared__ _Float16 Ks[128 * 64];   // [key][d]
  __shared__ _Float16 Vs[64 * 128];   // [d][key] (from vt)

  const int tid = threadIdx.x;
  const int w = tid >> 6, lane = tid & 63;
  const int l4 = lane & 15, quad = lane >> 4;
  const int q0 = blockIdx.x * 128;
  const int bh = blockIdx.y;
  const _Float16* qbh = qg + bh * 262144;
  const _Float16* kbh = kg + bh * 262144;
  const _Float16* vbh = vtg + bh * 262144;

  // Q as B-operand frags: query = w*32 + nt*16 + l4, d = ks*32 + quad*8..+7
  half8 qf[2][2];
#pragma unroll
  for (int nt = 0; nt < 2; ++nt)
#pragma unroll
    for (int ks = 0; ks < 2; ++ks)
      qf[nt][ks] = *(const half8*)(qbh + (q0 + w * 32 + nt * 16 + l4) * 64 + ks * 32 + quad * 8);

  const floatx4 zero = {0.f, 0.f, 0.f, 0.f};
  floatx4 OT[4][2];                  // [d-tile][q-tile], row=quad*4+r=d, col=l4=query
  float m_st[2], l_st[2];
#pragma unroll
  for (int md = 0; md < 4; ++md)
#pragma unroll
    for (int nt = 0; nt < 2; ++nt) OT[md][nt] = zero;
#pragma unroll
  for (int nt = 0; nt < 2; ++nt) { m_st[nt] = -1e30f; l_st[nt] = 0.f; }

  for (int t = 0; t < 5; ++t) {
    const int kv0 = q0 + (t - 2) * 128;
    if (kv0 < 0 || kv0 >= 4096) continue;  // block-uniform

    // stage K [128][64] and Vt [64][128], 3-bit XOR chunk swizzle
#pragma unroll
    for (int i = 0; i < 4; ++i) {
      const int p = i * 256 + tid;
      const int rk = p >> 3, ck = (p & 7) ^ (rk & 7);
      async_copy16(kbh + (kv0 + rk) * 64 + ck * 8, Ks + (i * 256 + w * 64) * 8);
      const int rv = p >> 4, cv = (p & 15) ^ (rv & 7);
      async_copy16(vbh + rv * 4096 + kv0 + cv * 8, Vs + (i * 256 + w * 64) * 8);
    }
    __syncthreads();

    const bool edge = (t == 0 || t == 4);
#pragma unroll
    for (int hf = 0; hf < 2; ++hf) {
      const int kb = hf * 64;  // key base within staged tile

      // ST = K Q^T : 64 keys (4 mtiles) x 32 queries (2 ntiles)
      floatx4 ST[4][2];
#pragma unroll
      for (int m = 0; m < 4; ++m)
#pragma unroll
        for (int nt = 0; nt < 2; ++nt) ST[m][nt] = zero;
#pragma unroll
      for (int ks = 0; ks < 2; ++ks)
#pragma unroll
        for (int m = 0; m < 4; ++m) {
          const half8 kf = *(const half8*)(Ks + (kb + m * 16 + l4) * 64 +
                                           ((ks * 4 + quad) ^ (l4 & 7)) * 8);
#pragma unroll
          for (int nt = 0; nt < 2; ++nt)
            ST[m][nt] = __builtin_amdgcn_mfma_f32_16x16x32_f16(kf, qf[nt][ks], ST[m][nt], 0, 0, 0);
        }

      if (edge) {  // band mask |key - query| <= 256, only on edge tiles
#pragma unroll
        for (int m = 0; m < 4; ++m)
#pragma unroll
          for (int r = 0; r < 4; ++r) {
            const int key = kv0 + kb + m * 16 + quad * 4 + r;
#pragma unroll
            for (int nt = 0; nt < 2; ++nt) {
              const int d = key - (q0 + w * 32 + nt * 16 + l4);
              if (d < -256 || d > 256) ST[m][nt][r] = -1e30f;
            }
          }
      }

      // online softmax per query column (lane-local over 16 keys + 2 shuffles)
#pragma unroll
      for (int nt = 0; nt < 2; ++nt) {
        float mx = -1e30f;
#pragma unroll
        for (int m = 0; m < 4; ++m)
#pragma unroll
          for (int r = 0; r < 4; ++r) mx = fmaxf(mx, ST[m][nt][r]);
        mx = fmaxf(mx, __shfl_xor(mx, 16));
        mx = fmaxf(mx, __shfl_xor(mx, 32));
        const float mnew = fmaxf(m_st[nt], mx);
        const float alpha = exp2f(m_st[nt] - mnew);
        m_st[nt] = mnew;
        float rs = 0.f;
#pragma unroll
        for (int m = 0; m < 4; ++m)
#pragma unroll
          for (int r = 0; r < 4; ++r) {
            const float pv = exp2f(ST[m][nt][r] - mnew);
            ST[m][nt][r] = pv;
            rs += pv;
          }
        rs += __shfl_xor(rs, 16);
        rs += __shfl_xor(rs, 32);
        l_st[nt] = l_st[nt] * alpha + rs;
#pragma unroll
        for (int md = 0; md < 4; ++md)
#pragma unroll
          for (int r = 0; r < 4; ++r) OT[md][nt][r] *= alpha;
      }

      // O^T += V^T P^T via 16x16x16 mfma; P B-frag = packed ST C-frag
#pragma unroll
      for (int m = 0; m < 4; ++m) {
        half4v pb[2];
#pragma unroll
        for (int nt = 0; nt < 2; ++nt) {
          const auto lo = __builtin_amdgcn_cvt_pkrtz(ST[m][nt][0], ST[m][nt][1]);
          const auto hi = __builtin_amdgcn_cvt_pkrtz(ST[m][nt][2], ST[m][nt][3]);
          pb[nt][0] = (_Float16)lo[0]; pb[nt][1] = (_Float16)lo[1];
          pb[nt][2] = (_Float16)hi[0]; pb[nt][3] = (_Float16)hi[1];
        }
#pragma unroll
        for (int md = 0; md < 4; ++md) {
          // V^T A-frag: m-dim = d = md*16+l4, k = keys kb + m*16 + quad*4..+3
          const half4v vf = *(const half4v*)(Vs + (md * 16 + l4) * 128 +
                                             (((hf * 8 + m * 2 + (quad >> 1)) ^ (l4 & 7)) * 8 +
                                              (quad & 1) * 4));
#pragma unroll
          for (int nt = 0; nt < 2; ++nt)
            OT[md][nt] = __builtin_amdgcn_mfma_f32_16x16x16f16(vf, pb[nt], OT[md][nt], 0, 0, 0);
        }
      }
    }
    __syncthreads();  // protect Ks/Vs before next tile's staging
  }

  // epilogue: O^T lane holds (d = md*16+quad*4+r, query = nt*16+l4); r is
  // contiguous in d -> packed half4 (8 B) stores.
  const int b = bh >> 4, hh = bh & 15;
#pragma unroll
  for (int nt = 0; nt < 2; ++nt) {
    const float inv_l = 1.f / l_st[nt];
    const int s = q0 + w * 32 + nt * 16 + l4;
#pragma unroll
    for (int md = 0; md < 4; ++md) {
      half4v o;
#pragma unroll
      for (int r = 0; r < 4; ++r) o[r] = (_Float16)(OT[md][nt][r] * inv_l);
      *(half4v*)(ctx + (b * 4096 + s) * 1024 + hh * 64 + md * 16 + quad * 4) = o;
    }
  }
}

// ---------------------------------------------------------------- launch
extern "C" void kernel_launch(void* const* d_in, const int* in_sizes, int n_in,
                              void* d_out, int out_size, void* d_ws, size_t ws_size,
                              hipStream_t stream) {
  const float* x  = (const float*)d_in[0];
  const float* Wq = (const float*)d_in[1];
  const float* bq = (const float*)d_in[2];
  const float* Wk = (const float*)d_in[3];
  const float* bk = (const float*)d_in[4];
  const float* Wv = (const float*)d_in[5];
  const float* bv = (const float*)d_in[6];
  const float* Wo = (const float*)d_in[7];
  const float* bo = (const float*)d_in[8];

  _Float16* ws   = (_Float16*)d_ws;       // all offsets in halfs
  _Float16* xh   = ws;                    // 8388608
  _Float16* wqh  = ws + 8388608;          // 1048576 each
  _Float16* wkh  = ws + 9437184;
  _Float16* wvh  = ws + 10485760;
  _Float16* woh  = ws + 11534336;
  _Float16* qh   = ws + 12582912;         // [b,h,s,d] fp16, rope+scale applied
  _Float16* kh   = ws + 20971520;         // [b,h,s,d] fp16, rope applied
  _Float16* vh   = ws + 29360128;         // [b,h,s,d] fp16
  _Float16* vth  = ws + 37748736;         // [b,h,d,s]
  _Float16* ctxh = xh;                    // reuse: x dead after QKV GEMM

  convert_kernel<<<12288, 256, 0, stream>>>(x, Wq, Wk, Wv, Wo, ws);
  gemm_qkv_kernel<<<dim3(64, 8, 3), 256, 0, stream>>>(xh, wqh, wkh, wvh,
                                                      bq, bk, bv, qh, kh, vh);
  transpose_v<<<dim3(64, 32), 256, 0, stream>>>(vh, vth);
  attn_kernel<<<dim3(32, 32), 256, 0, stream>>>(qh, kh, vth, ctxh);
  gemm_out_kernel<<<dim3(64, 8), 256, 0, stream>>>(ctxh, woh, bo, (float*)d_out);
}

// Round 4
// 256.570 us; speedup vs baseline: 1.4503x; 1.0071x over previous
//
#include <hip/hip_runtime.h>

// LongformerAttention on MI355X (gfx950), fp16 MFMA pipeline, round 4.
// R4 (GEMMs only; attn carried from R3 verbatim):
//  - XCD-aware block swizzle (bid&7 = XCD): each XCD's L2 holds its 2 MB
//    x-slice + 256 KB W-tile -> staging served from local L2 not L3.
//  - BK=64: halves the per-iter vmcnt(0)+barrier drains (32->16).
//  - gemm_qkv epilogue: acc -> LDS (stride 132) -> half8 coalesced stores.

typedef _Float16 half8 __attribute__((ext_vector_type(8)));
typedef _Float16 half4v __attribute__((ext_vector_type(4)));
typedef float floatx4 __attribute__((ext_vector_type(4)));

typedef __attribute__((address_space(3))) unsigned int lds_u32;
typedef const __attribute__((address_space(1))) unsigned int glb_u32;

__device__ __forceinline__ void async_copy16(const void* g, void* l) {
  // global -> LDS direct, 16 B/lane. LDS dest = wave-uniform base + lane*16.
  __builtin_amdgcn_global_load_lds((glb_u32*)g, (lds_u32*)l, 16, 0, 0);
}

// ---------------------------------------------------------------- convert
__global__ __launch_bounds__(256) void convert_kernel(
    const float* __restrict__ x, const float* __restrict__ wq,
    const float* __restrict__ wk, const float* __restrict__ wv,
    const float* __restrict__ wo, _Float16* __restrict__ dst) {
  const int e0 = (blockIdx.x * 256 + threadIdx.x) * 4;
  const float* src; int off;
  if      (e0 <  8388608) { src = x;  off = e0; }
  else if (e0 <  9437184) { src = wq; off = e0 -  8388608; }
  else if (e0 < 10485760) { src = wk; off = e0 -  9437184; }
  else if (e0 < 11534336) { src = wv; off = e0 - 10485760; }
  else                    { src = wo; off = e0 - 11534336; }
  const float4 f = *(const float4*)(src + off);
  half4v h;
  h[0] = (_Float16)f.x; h[1] = (_Float16)f.y;
  h[2] = (_Float16)f.z; h[3] = (_Float16)f.w;
  *(half4v*)(dst + e0) = h;
}

// ---------------------------------------------------------------- QKV GEMM
// out[m,n] = sum_k A[m,k]*W[n,k] + bias[n]; RoPE fused in epilogue (pair
// (n, n^1) in adjacent l4 lanes -> __shfl_xor(val,1)); q scaled by log2e/8.
// BK=64, XCD swizzle, LDS-coalesced stores.
__global__ __launch_bounds__(256, 2) void gemm_qkv_kernel(
    const _Float16* __restrict__ A, const _Float16* __restrict__ w0,
    const _Float16* __restrict__ w1, const _Float16* __restrict__ w2,
    const float* __restrict__ b0, const float* __restrict__ b1,
    const float* __restrict__ b2, _Float16* __restrict__ o0,
    _Float16* __restrict__ o1, _Float16* __restrict__ o2) {
  __shared__ _Float16 smem[17408];          // 34.8 KB: staging 32 KB / epi 33.8 KB
  _Float16* As = smem;                      // [128][64] chunk-swizzled
  _Float16* Bs = smem + 8192;

  const int tid = threadIdx.x;
  const int w = tid >> 6, lane = tid & 63;
  const int l4 = lane & 15, quad = lane >> 4;
  const int wm = w & 1, wn = w >> 1;

  // XCD-aware decode: bid&7 = XCD slot; within an XCD: z outer, n mid, m fast.
  const int bid = blockIdx.x;
  const int xcd = bid & 7, li = bid >> 3;   // li in 0..191
  const int z = li >> 6, r_ = li & 63;
  const int n_l = r_ >> 3, m_l = r_ & 7;
  const int m0 = (xcd * 8 + m_l) * 128;
  const int n0 = n_l * 128;

  const _Float16* B; const float* bias; _Float16* out;
  if (z == 0)      { B = w0; bias = b0; out = o0; }
  else if (z == 1) { B = w1; bias = b1; out = o1; }
  else             { B = w2; bias = b2; out = o2; }
  const bool dorope = z < 2;
  const float scl = (z == 0) ? 0.18033688f : 1.0f;  // log2e/8

  const floatx4 zero = {0.f, 0.f, 0.f, 0.f};
  floatx4 acc[4][4];
#pragma unroll
  for (int i = 0; i < 4; ++i)
#pragma unroll
    for (int j = 0; j < 4; ++j) acc[i][j] = zero;

  for (int kt = 0; kt < 16; ++kt) {
    const int k0 = kt * 64;
#pragma unroll
    for (int i = 0; i < 4; ++i) {
      const int p = i * 256 + tid;          // 0..1023 = 128 rows x 8 chunks
      const int r = p >> 3;
      const int c = (p & 7) ^ (r & 7);      // 3-bit XOR chunk swizzle
      async_copy16(A + (m0 + r) * 1024 + k0 + c * 8, As + (i * 256 + w * 64) * 8);
      async_copy16(B + (n0 + r) * 1024 + k0 + c * 8, Bs + (i * 256 + w * 64) * 8);
    }
    __syncthreads();
#pragma unroll
    for (int ks = 0; ks < 2; ++ks) {
      half8 af[4], bf[4];
#pragma unroll
      for (int mt = 0; mt < 4; ++mt)
        af[mt] = *(const half8*)(As + (wm * 64 + mt * 16 + l4) * 64 +
                                 (((ks * 4 + quad) ^ (l4 & 7)) * 8));
#pragma unroll
      for (int nt = 0; nt < 4; ++nt)
        bf[nt] = *(const half8*)(Bs + (wn * 64 + nt * 16 + l4) * 64 +
                                 (((ks * 4 + quad) ^ (l4 & 7)) * 8));
#pragma unroll
      for (int mt = 0; mt < 4; ++mt)
#pragma unroll
        for (int nt = 0; nt < 4; ++nt)
          acc[mt][nt] = __builtin_amdgcn_mfma_f32_16x16x32_f16(af[mt], bf[nt], acc[mt][nt], 0, 0, 0);
    }
    __syncthreads();
  }

  // epilogue: bias + RoPE in C-layout, stash to LDS, coalesced half8 stores
  _Float16* tile = smem;                    // [128][132]
#pragma unroll
  for (int nt = 0; nt < 4; ++nt) {
    const int n = n0 + wn * 64 + nt * 16 + l4;
    const float bval = bias[n];
    const int hh = n >> 6;
    float c_ = 1.f, ss = 0.f;
    if (dorope) {
      const float freq = __expf((float)(n & 31) * -0.28782314f);  // ln(1e4)/32
      float s_;
      __sincosf((float)hh * freq, &s_, &c_);
      ss = (n & 1) ? s_ : -s_;
    }
#pragma unroll
    for (int mt = 0; mt < 4; ++mt)
#pragma unroll
      for (int r = 0; r < 4; ++r) {
        float val = acc[mt][nt][r] + bval;
        const float prt = __shfl_xor(val, 1);
        if (dorope) val = (val * c_ + prt * ss) * scl;
        tile[(wm * 64 + mt * 16 + quad * 4 + r) * 132 + wn * 64 + nt * 16 + l4] = (_Float16)val;
      }
  }
  __syncthreads();
#pragma unroll
  for (int j = 0; j < 8; ++j) {
    const int idx = j * 256 + tid;          // 128 rows x 16 col-chunks
    const int row = idx >> 4, cb = idx & 15;
    const int n = n0 + cb * 8;              // 8 contiguous cols, same head
    const int hh = n >> 6, dd = n & 63;
    const int m = m0 + row, bb = m >> 12, s = m & 4095;
    const half8 vals = *(const half8*)(tile + row * 132 + cb * 8);
    *(half8*)(out + ((bb * 16 + hh) * 4096 + s) * 64 + dd) = vals;
  }
}

// ---------------------------------------------------------------- out GEMM
// BK=64 + XCD swizzle; f32 output, direct stores (already 64 B/quad).
__global__ __launch_bounds__(256, 2) void gemm_out_kernel(
    const _Float16* __restrict__ A, const _Float16* __restrict__ B,
    const float* __restrict__ bias, float* __restrict__ out) {
  __shared__ _Float16 smem[16384];
  _Float16* As = smem;
  _Float16* Bs = smem + 8192;

  const int tid = threadIdx.x;
  const int w = tid >> 6, lane = tid & 63;
  const int l4 = lane & 15, quad = lane >> 4;
  const int wm = w & 1, wn = w >> 1;

  const int bid = blockIdx.x;
  const int xcd = bid & 7, li = bid >> 3;   // li in 0..63
  const int n_l = li >> 3, m_l = li & 7;
  const int m0 = (xcd * 8 + m_l) * 128;
  const int n0 = n_l * 128;

  const floatx4 zero = {0.f, 0.f, 0.f, 0.f};
  floatx4 acc[4][4];
#pragma unroll
  for (int i = 0; i < 4; ++i)
#pragma unroll
    for (int j = 0; j < 4; ++j) acc[i][j] = zero;

  for (int kt = 0; kt < 16; ++kt) {
    const int k0 = kt * 64;
#pragma unroll
    for (int i = 0; i < 4; ++i) {
      const int p = i * 256 + tid;
      const int r = p >> 3;
      const int c = (p & 7) ^ (r & 7);
      async_copy16(A + (m0 + r) * 1024 + k0 + c * 8, As + (i * 256 + w * 64) * 8);
      async_copy16(B + (n0 + r) * 1024 + k0 + c * 8, Bs + (i * 256 + w * 64) * 8);
    }
    __syncthreads();
#pragma unroll
    for (int ks = 0; ks < 2; ++ks) {
      half8 af[4], bf[4];
#pragma unroll
      for (int mt = 0; mt < 4; ++mt)
        af[mt] = *(const half8*)(As + (wm * 64 + mt * 16 + l4) * 64 +
                                 (((ks * 4 + quad) ^ (l4 & 7)) * 8));
#pragma unroll
      for (int nt = 0; nt < 4; ++nt)
        bf[nt] = *(const half8*)(Bs + (wn * 64 + nt * 16 + l4) * 64 +
                                 (((ks * 4 + quad) ^ (l4 & 7)) * 8));
#pragma unroll
      for (int mt = 0; mt < 4; ++mt)
#pragma unroll
        for (int nt = 0; nt < 4; ++nt)
          acc[mt][nt] = __builtin_amdgcn_mfma_f32_16x16x32_f16(af[mt], bf[nt], acc[mt][nt], 0, 0, 0);
    }
    __syncthreads();
  }

#pragma unroll
  for (int nt = 0; nt < 4; ++nt) {
    const int n = n0 + wn * 64 + nt * 16 + l4;
    const float bval = bias[n];
#pragma unroll
    for (int mt = 0; mt < 4; ++mt)
#pragma unroll
      for (int r = 0; r < 4; ++r) {
        const int m = m0 + wm * 64 + mt * 16 + quad * 4 + r;
        out[m * 1024 + n] = acc[mt][nt][r] + bval;
      }
  }
}

// ---------------------------------------------------------------- V transpose
__global__ __launch_bounds__(256) void transpose_v(const _Float16* __restrict__ v,
                                                   _Float16* __restrict__ vt) {
  __shared__ _Float16 tile[64 * 70];
  const int t = threadIdx.x;
  const int bh = blockIdx.y, s0 = blockIdx.x * 64;
  const _Float16* src = v + (bh * 4096 + s0) * 64;
#pragma unroll
  for (int i = 0; i < 2; ++i) {
    const int c = i * 256 + t;
    const int row = c >> 3, cb = c & 7;
    const half8 d = *(const half8*)(src + row * 64 + cb * 8);
#pragma unroll
    for (int u = 0; u < 8; ++u) tile[(cb * 8 + u) * 70 + row] = d[u];
  }
  __syncthreads();
  _Float16* dst = vt + bh * 262144 + s0;
#pragma unroll
  for (int i = 0; i < 2; ++i) {
    const int c = i * 256 + t;
    const int dd = c >> 3, scb = c & 7;
    half8 d;
#pragma unroll
    for (int u = 0; u < 8; ++u) d[u] = tile[dd * 70 + scb * 8 + u];
    *(half8*)(dst + dd * 4096 + scb * 8) = d;
  }
}

// ---------------------------------------------------------------- attention
// S^T formulation (R3, unchanged): ST = K*Q^T per 64-key half-tile; ST C-layout
// IS the B-operand layout of mfma_f32_16x16x16f16 -> P feeds PV from regs.
__global__ __launch_bounds__(256, 2) void attn_kernel(
    const _Float16* __restrict__ qg, const _Float16* __restrict__ kg,
    const _Float16* __restrict__ vtg, _Float16* __restrict__ ctx) {
  __shared__ _Float16 Ks[128 * 64];   // [key][d]
  __shared__ _Float16 Vs[64 * 128];   // [d][key] (from vt)

  const int tid = threadIdx.x;
  const int w = tid >> 6, lane = tid & 63;
  const int l4 = lane & 15, quad = lane >> 4;
  const int q0 = blockIdx.x * 128;
  const int bh = blockIdx.y;
  const _Float16* qbh = qg + bh * 262144;
  const _Float16* kbh = kg + bh * 262144;
  const _Float16* vbh = vtg + bh * 262144;

  half8 qf[2][2];
#pragma unroll
  for (int nt = 0; nt < 2; ++nt)
#pragma unroll
    for (int ks = 0; ks < 2; ++ks)
      qf[nt][ks] = *(const half8*)(qbh + (q0 + w * 32 + nt * 16 + l4) * 64 + ks * 32 + quad * 8);

  const floatx4 zero = {0.f, 0.f, 0.f, 0.f};
  floatx4 OT[4][2];
  float m_st[2], l_st[2];
#pragma unroll
  for (int md = 0; md < 4; ++md)
#pragma unroll
    for (int nt = 0; nt < 2; ++nt) OT[md][nt] = zero;
#pragma unroll
  for (int nt = 0; nt < 2; ++nt) { m_st[nt] = -1e30f; l_st[nt] = 0.f; }

  for (int t = 0; t < 5; ++t) {
    const int kv0 = q0 + (t - 2) * 128;
    if (kv0 < 0 || kv0 >= 4096) continue;

#pragma unroll
    for (int i = 0; i < 4; ++i) {
      const int p = i * 256 + tid;
      const int rk = p >> 3, ck = (p & 7) ^ (rk & 7);
      async_copy16(kbh + (kv0 + rk) * 64 + ck * 8, Ks + (i * 256 + w * 64) * 8);
      const int rv = p >> 4, cv = (p & 15) ^ (rv & 7);
      async_copy16(vbh + rv * 4096 + kv0 + cv * 8, Vs + (i * 256 + w * 64) * 8);
    }
    __syncthreads();

    const bool edge = (t == 0 || t == 4);
#pragma unroll
    for (int hf = 0; hf < 2; ++hf) {
      const int kb = hf * 64;

      floatx4 ST[4][2];
#pragma unroll
      for (int m = 0; m < 4; ++m)
#pragma unroll
        for (int nt = 0; nt < 2; ++nt) ST[m][nt] = zero;
#pragma unroll
      for (int ks = 0; ks < 2; ++ks)
#pragma unroll
        for (int m = 0; m < 4; ++m) {
          const half8 kf = *(const half8*)(Ks + (kb + m * 16 + l4) * 64 +
                                           ((ks * 4 + quad) ^ (l4 & 7)) * 8);
#pragma unroll
          for (int nt = 0; nt < 2; ++nt)
            ST[m][nt] = __builtin_amdgcn_mfma_f32_16x16x32_f16(kf, qf[nt][ks], ST[m][nt], 0, 0, 0);
        }

      if (edge) {
#pragma unroll
        for (int m = 0; m < 4; ++m)
#pragma unroll
          for (int r = 0; r < 4; ++r) {
            const int key = kv0 + kb + m * 16 + quad * 4 + r;
#pragma unroll
            for (int nt = 0; nt < 2; ++nt) {
              const int d = key - (q0 + w * 32 + nt * 16 + l4);
              if (d < -256 || d > 256) ST[m][nt][r] = -1e30f;
            }
          }
      }

#pragma unroll
      for (int nt = 0; nt < 2; ++nt) {
        float mx = -1e30f;
#pragma unroll
        for (int m = 0; m < 4; ++m)
#pragma unroll
          for (int r = 0; r < 4; ++r) mx = fmaxf(mx, ST[m][nt][r]);
        mx = fmaxf(mx, __shfl_xor(mx, 16));
        mx = fmaxf(mx, __shfl_xor(mx, 32));
        const float mnew = fmaxf(m_st[nt], mx);
        const float alpha = exp2f(m_st[nt] - mnew);
        m_st[nt] = mnew;
        float rs = 0.f;
#pragma unroll
        for (int m = 0; m < 4; ++m)
#pragma unroll
          for (int r = 0; r < 4; ++r) {
            const float pv = exp2f(ST[m][nt][r] - mnew);
            ST[m][nt][r] = pv;
            rs += pv;
          }
        rs += __shfl_xor(rs, 16);
        rs += __shfl_xor(rs, 32);
        l_st[nt] = l_st[nt] * alpha + rs;
#pragma unroll
        for (int md = 0; md < 4; ++md)
#pragma unroll
          for (int r = 0; r < 4; ++r) OT[md][nt][r] *= alpha;
      }

#pragma unroll
      for (int m = 0; m < 4; ++m) {
        half4v pb[2];
#pragma unroll
        for (int nt = 0; nt < 2; ++nt) {
          const auto lo = __builtin_amdgcn_cvt_pkrtz(ST[m][nt][0], ST[m][nt][1]);
          const auto hi = __builtin_amdgcn_cvt_pkrtz(ST[m][nt][2], ST[m][nt][3]);
          pb[nt][0] = (_Float16)lo[0]; pb[nt][1] = (_Float16)lo[1];
          pb[nt][2] = (_Float16)hi[0]; pb[nt][3] = (_Float16)hi[1];
        }
#pragma unroll
        for (int md = 0; md < 4; ++md) {
          const half4v vf = *(const half4v*)(Vs + (md * 16 + l4) * 128 +
                                             (((hf * 8 + m * 2 + (quad >> 1)) ^ (l4 & 7)) * 8 +
                                              (quad & 1) * 4));
#pragma unroll
          for (int nt = 0; nt < 2; ++nt)
            OT[md][nt] = __builtin_amdgcn_mfma_f32_16x16x16f16(vf, pb[nt], OT[md][nt], 0, 0, 0);
        }
      }
    }
    __syncthreads();
  }

  const int b = bh >> 4, hh = bh & 15;
#pragma unroll
  for (int nt = 0; nt < 2; ++nt) {
    const float inv_l = 1.f / l_st[nt];
    const int s = q0 + w * 32 + nt * 16 + l4;
#pragma unroll
    for (int md = 0; md < 4; ++md) {
      half4v o;
#pragma unroll
      for (int r = 0; r < 4; ++r) o[r] = (_Float16)(OT[md][nt][r] * inv_l);
      *(half4v*)(ctx + (b * 4096 + s) * 1024 + hh * 64 + md * 16 + quad * 4) = o;
    }
  }
}

// ---------------------------------------------------------------- launch
extern "C" void kernel_launch(void* const* d_in, const int* in_sizes, int n_in,
                              void* d_out, int out_size, void* d_ws, size_t ws_size,
                              hipStream_t stream) {
  const float* x  = (const float*)d_in[0];
  const float* Wq = (const float*)d_in[1];
  const float* bq = (const float*)d_in[2];
  const float* Wk = (const float*)d_in[3];
  const float* bk = (const float*)d_in[4];
  const float* Wv = (const float*)d_in[5];
  const float* bv = (const float*)d_in[6];
  const float* Wo = (const float*)d_in[7];
  const float* bo = (const float*)d_in[8];

  _Float16* ws   = (_Float16*)d_ws;       // all offsets in halfs
  _Float16* xh   = ws;                    // 8388608
  _Float16* wqh  = ws + 8388608;          // 1048576 each
  _Float16* wkh  = ws + 9437184;
  _Float16* wvh  = ws + 10485760;
  _Float16* woh  = ws + 11534336;
  _Float16* qh   = ws + 12582912;         // [b,h,s,d] fp16, rope+scale applied
  _Float16* kh   = ws + 20971520;         // [b,h,s,d] fp16, rope applied
  _Float16* vh   = ws + 29360128;         // [b,h,s,d] fp16
  _Float16* vth  = ws + 37748736;         // [b,h,d,s]
  _Float16* ctxh = xh;                    // reuse: x dead after QKV GEMM

  convert_kernel<<<12288, 256, 0, stream>>>(x, Wq, Wk, Wv, Wo, ws);
  gemm_qkv_kernel<<<1536, 256, 0, stream>>>(xh, wqh, wkh, wvh,
                                            bq, bk, bv, qh, kh, vh);
  transpose_v<<<dim3(64, 32), 256, 0, stream>>>(vh, vth);
  attn_kernel<<<dim3(32, 32), 256, 0, stream>>>(qh, kh, vth, ctxh);
  gemm_out_kernel<<<512, 256, 0, stream>>>(ctxh, woh, bo, (float*)d_out);
}